// Round 8
// baseline (19.091 us; speedup 1.0000x reference)
//
#include <hip/hip_runtime.h>
#include <math.h>

#define DIM_   128
#define NAT_   16
#define NTOT_  1024
#define BMOL_  64
#define OFFB_  1008.0f
#define EPSF_  1e-12f

// Kernel A: 128 blocks (2 per molecule) x 1024 threads, WAVE-SPECIALIZED.
//   threads 0..511   = compute group: contri (4 atoms/thread, 128-k loop with
//                      float4 LDS reads) -> message -> L2 norm -> mpsn.
//   threads 512..1023 = gather group: 32 E_bond row-gathers issued right after
//                      barrier 1, consumed after mpsn is ready (overlap).
// Separate waves => separate vmcnt queues => gather latency hides under compute.
__global__ __launch_bounds__(1024) void kA(const int* __restrict__ fp,
                                           const float* __restrict__ Efp,
                                           const float* __restrict__ Wfp,
                                           const float* __restrict__ bfp,
                                           const float* __restrict__ adj,
                                           const int* __restrict__ bidx,
                                           const float* __restrict__ Ebond,
                                           float* __restrict__ TnP_g,   // [128,128]
                                           float* __restrict__ SbP_g,   // [128,128]
                                           float* __restrict__ Mb_g) {  // [64,128]
    const int b = blockIdx.x;
    const int m = b >> 1, h = b & 1, base = m * NAT_;
    const int t = threadIdx.x;
    const int c = t & 127;
    const bool isGather = (t >= 512);

    __shared__ float mpsS[NAT_][DIM_];      // embeddings -> mpsn
    __shared__ float conS[NAT_][DIM_];
    __shared__ float adjS[NAT_][NAT_];
    __shared__ float redS[NAT_][2];
    __shared__ float nrmS[NAT_];
    __shared__ float sb8[8][DIM_];
    __shared__ float tnp8[8][DIM_];

    // ---- embeddings: all threads, 2 rows each ----
    {
        const int j = t >> 7;               // 0..7
        mpsS[j][c]     = Efp[(size_t)fp[base + j]     * DIM_ + c];
        mpsS[j + 8][c] = Efp[(size_t)fp[base + j + 8] * DIM_ + c];
    }
    if (t < 256) {
        const int j = t >> 4, i = t & 15;
        adjS[j][i] = adj[(size_t)(base + j) * NTOT_ + base + i];
    }

    // gather group: preload own 2 atoms' bond-index rows (wave-uniform, L1/L2)
    int bb0[NAT_], bb1[NAT_];
    const int g = (t - 512) >> 7;           // 0..3 (valid for gather threads)
    const int jg0 = 8 * h + 2 * g, jg1 = jg0 + 1;
    if (isGather) {
        const size_t r0 = (size_t)(base + jg0) * NTOT_ + base;
        const size_t r1 = (size_t)(base + jg1) * NTOT_ + base;
        #pragma unroll
        for (int i = 0; i < NAT_; ++i) bb0[i] = bidx[r0 + i];
        #pragma unroll
        for (int i = 0; i < NAT_; ++i) bb1[i] = bidx[r1 + i];
    }
    __syncthreads();

    float ev0[NAT_], ev1[NAT_];
    float nsq0 = 0.0f, nsq1 = 0.0f;
    float msv[4];
    const int q = t >> 7;                   // compute group: atom quad 0..3

    if (isGather) {
        // ---- issue 32 independent gathers; only this wave waits on them ----
        #pragma unroll
        for (int i = 0; i < NAT_; ++i) ev0[i] = Ebond[(size_t)bb0[i] * DIM_ + c];
        #pragma unroll
        for (int i = 0; i < NAT_; ++i) ev1[i] = Ebond[(size_t)bb1[i] * DIM_ + c];
        const float e0 = Ebond[c];
        nsq0 = nsq1 = OFFB_ * e0 * e0;
        #pragma unroll
        for (int i = 0; i < NAT_; ++i) { nsq0 += ev0[i] * ev0[i]; nsq1 += ev1[i] * ev1[i]; }
    } else {
        // ---- contri for atoms 4q..4q+3 ----
        float acc0 = bfp[c], acc1 = acc0, acc2 = acc0, acc3 = acc0;
        #pragma unroll 4
        for (int k = 0; k < DIM_; k += 4) {
            const float4 m0 = *reinterpret_cast<const float4*>(&mpsS[4 * q + 0][k]);
            const float4 m1 = *reinterpret_cast<const float4*>(&mpsS[4 * q + 1][k]);
            const float4 m2 = *reinterpret_cast<const float4*>(&mpsS[4 * q + 2][k]);
            const float4 m3 = *reinterpret_cast<const float4*>(&mpsS[4 * q + 3][k]);
            const float w0 = Wfp[(size_t)(k + 0) * DIM_ + c];
            const float w1 = Wfp[(size_t)(k + 1) * DIM_ + c];
            const float w2 = Wfp[(size_t)(k + 2) * DIM_ + c];
            const float w3 = Wfp[(size_t)(k + 3) * DIM_ + c];
            acc0 += m0.x * w0 + m0.y * w1 + m0.z * w2 + m0.w * w3;
            acc1 += m1.x * w0 + m1.y * w1 + m1.z * w2 + m1.w * w3;
            acc2 += m2.x * w0 + m2.y * w1 + m2.z * w2 + m2.w * w3;
            acc3 += m3.x * w0 + m3.y * w1 + m3.z * w2 + m3.w * w3;
        }
        conS[4 * q + 0][c] = fmaxf(acc0, 0.0f);
        conS[4 * q + 1][c] = fmaxf(acc1, 0.0f);
        conS[4 * q + 2][c] = fmaxf(acc2, 0.0f);
        conS[4 * q + 3][c] = fmaxf(acc3, 0.0f);
    }
    __syncthreads();

    if (!isGather) {
        // ---- message + row L2 norm for atoms 4q..4q+3 ----
        #pragma unroll
        for (int jj = 0; jj < 4; ++jj) {
            const int j = 4 * q + jj;
            float x = mpsS[j][c];
            #pragma unroll
            for (int i = 0; i < NAT_; ++i) x += adjS[j][i] * conS[i][c];
            msv[jj] = x;
            float v = x * x;
            #pragma unroll
            for (int o = 32; o > 0; o >>= 1) v += __shfl_xor(v, o, 64);
            if ((t & 63) == 0) redS[j][(t >> 6) & 1] = v;
        }
    }
    __syncthreads();
    if (t < NAT_) nrmS[t] = fmaxf(sqrtf(redS[t][0] + redS[t][1]), EPSF_);
    __syncthreads();
    if (!isGather) {
        #pragma unroll
        for (int jj = 0; jj < 4; ++jj) {
            const int j = 4 * q + jj;
            mpsS[j][c] = msv[jj] / nrmS[j];
        }
    }
    __syncthreads();

    if (isGather) {
        // ---- consume gathers: msc + tj for owned atoms jg0, jg1 ----
        const float msc0 = mpsS[jg0][c] / fmaxf(sqrtf(nsq0), EPSF_);
        const float msc1 = mpsS[jg1][c] / fmaxf(sqrtf(nsq1), EPSF_);
        float tj0 = 0.0f, tj1 = 0.0f;
        #pragma unroll
        for (int i = 0; i < NAT_; ++i) {
            const float mi = mpsS[i][c];
            tj0 += ev0[i] * mi;
            tj1 += ev1[i] * mi;
        }
        sb8[2 * g + 0][c]  = msc0;
        sb8[2 * g + 1][c]  = msc1;
        tnp8[2 * g + 0][c] = msc0 * tj0;
        tnp8[2 * g + 1][c] = msc1 * tj1;
    }
    __syncthreads();

    // ---- outputs ----
    if (t < 128) {
        float v = 0.0f;
        #pragma unroll
        for (int r = 0; r < 8; ++r) v += sb8[r][t];
        SbP_g[(size_t)b * DIM_ + t] = v;
    } else if (t < 256) {
        const int cc = t - 128;
        float v = 0.0f;
        #pragma unroll
        for (int r = 0; r < 8; ++r) v += tnp8[r][cc];
        TnP_g[(size_t)b * DIM_ + cc] = v;
    } else if (t < 384 && h == 0) {
        const int cc = t - 256;
        float v = 0.0f;
        #pragma unroll
        for (int j = 0; j < NAT_; ++j) v += mpsS[j][cc];
        Mb_g[(size_t)m * DIM_ + cc] = v;
    }
}

// Kernel B: 64 blocks x 512 threads. S -> tn -> MLP -> out, slot-split d-loops.
__global__ __launch_bounds__(512) void kB(const float* __restrict__ Ebond,
                                          const float* __restrict__ TnP_g,
                                          const float* __restrict__ SbP_g,
                                          const float* __restrict__ Mb_g,
                                          const float* __restrict__ W0, const float* __restrict__ b0,
                                          const float* __restrict__ W1, const float* __restrict__ b1,
                                          const float* __restrict__ Wp, const float* __restrict__ bp,
                                          float* __restrict__ out) {
    const int m = blockIdx.x;
    const int t = threadIdx.x;
    const int c = t & 127;
    const int s = t >> 7;
    __shared__ float w4[4][DIM_];
    __shared__ float vS[DIM_];
    __shared__ float tnS[DIM_];
    __shared__ float r2[2];

    {
        float S = 0.0f;
        float tv[32];
        #pragma unroll
        for (int r = 0; r < 32; ++r)
            tv[r] = SbP_g[(size_t)(s * 32 + r) * DIM_ + c];
        #pragma unroll
        for (int r = 0; r < 32; ++r) S += tv[r];
        w4[s][c] = S;
    }
    __syncthreads();
    if (s == 0) {
        const float Sall = w4[0][c] + w4[1][c] + w4[2][c] + w4[3][c];
        const float Sb_m = SbP_g[(size_t)(2 * m) * DIM_ + c] + SbP_g[(size_t)(2 * m + 1) * DIM_ + c];
        const float Tn_m = TnP_g[(size_t)(2 * m) * DIM_ + c] + TnP_g[(size_t)(2 * m + 1) * DIM_ + c];
        vS[c] = Tn_m + Ebond[c] * (Sall - Sb_m) * Mb_g[(size_t)m * DIM_ + c];
    }
    __syncthreads();

    {
        float a1 = 0.0f;
        #pragma unroll 8
        for (int r = 0; r < 32; ++r) {
            const int d = s * 32 + r;
            a1 += vS[d] * W0[(size_t)d * DIM_ + c];
        }
        w4[s][c] = a1;
    }
    __syncthreads();
    if (s == 0) tnS[c] = fmaxf(w4[0][c] + w4[1][c] + w4[2][c] + w4[3][c] + b0[c], 0.0f);
    __syncthreads();
    {
        float a2 = 0.0f;
        #pragma unroll 8
        for (int r = 0; r < 32; ++r) {
            const int d = s * 32 + r;
            a2 += tnS[d] * W1[(size_t)d * DIM_ + c];
        }
        w4[s][c] = a2;
    }
    __syncthreads();
    if (s == 0) {
        const float x1 = fmaxf(w4[0][c] + w4[1][c] + w4[2][c] + w4[3][c] + b1[c], 0.0f);
        float vv = x1 * Wp[c];
        #pragma unroll
        for (int o = 32; o > 0; o >>= 1) vv += __shfl_xor(vv, o, 64);
        if ((c & 63) == 0) r2[c >> 6] = vv;
    }
    __syncthreads();
    if (t == 0) out[m] = r2[0] + r2[1] + bp[0];
}

extern "C" void kernel_launch(void* const* d_in, const int* in_sizes, int n_in,
                              void* d_out, int out_size, void* d_ws, size_t ws_size,
                              hipStream_t stream) {
    const int*   fingerprints = (const int*)  d_in[0];
    const float* adjacency    = (const float*)d_in[1];
    const int*   bond_index   = (const int*)  d_in[2];
    const float* E_fp         = (const float*)d_in[3];
    const float* E_bond       = (const float*)d_in[4];
    const float* W_fp         = (const float*)d_in[5];
    const float* b_fp         = (const float*)d_in[6];
    const float* W_out0       = (const float*)d_in[7];
    const float* b_out0       = (const float*)d_in[8];
    const float* W_out1       = (const float*)d_in[9];
    const float* b_out1       = (const float*)d_in[10];
    const float* W_prop       = (const float*)d_in[11];
    const float* b_prop       = (const float*)d_in[12];
    float* out = (float*)d_out;

    float* ws = (float*)d_ws;
    const size_t PD = (size_t)128 * DIM_;
    float* TnP = ws;                 // [128,128]
    float* SbP = ws + PD;            // [128,128]
    float* Mb  = ws + 2 * PD;        // [64,128]

    kA<<<128, 1024, 0, stream>>>(fingerprints, E_fp, W_fp, b_fp, adjacency, bond_index,
                                 E_bond, TnP, SbP, Mb);
    kB<<<BMOL_, 512, 0, stream>>>(E_bond, TnP, SbP, Mb,
                                  W_out0, b_out0, W_out1, b_out1, W_prop, b_prop, out);
}

// Round 9
// 18.443 us; speedup vs baseline: 1.0351x; 1.0351x over previous
//
#include <hip/hip_runtime.h>
#include <math.h>

#define DIM_   128
#define NAT_   16
#define NTOT_  1024
#define BMOL_  64
#define OFFB_  1008.0f
#define EPSF_  1e-12f

// Kernel A: 128 blocks (2 per molecule) x 1024 threads (16 waves).
// Block b: m = b>>1, half h = b&1 (owns atoms 8h..8h+7 for the bond gather).
// Thread t: c = t&127 (dim), s = t>>7 (slot 0..7).
// Full contri/message/L2norm computed in every block (cheap, duplicated x2);
// bond gather + Sb/TnIn partials only for the 8 owned atoms (16 loads/thread).
__global__ __launch_bounds__(1024) void kA(const int* __restrict__ fp,
                                           const float* __restrict__ Efp,
                                           const float* __restrict__ Wfp,
                                           const float* __restrict__ bfp,
                                           const float* __restrict__ adj,
                                           const int* __restrict__ bidx,
                                           const float* __restrict__ Ebond,
                                           float* __restrict__ TnP_g,   // [128,128]
                                           float* __restrict__ SbP_g,   // [128,128]
                                           float* __restrict__ Mb_g) {  // [64,128]
    const int b = blockIdx.x;
    const int m = b >> 1, h = b & 1, base = m * NAT_;
    const int t = threadIdx.x;
    const int c = t & 127;
    const int s = t >> 7;
    const int j0 = 2 * s, j1 = 2 * s + 1;   // contri/message atoms
    const int jg = 8 * h + s;               // gather-owned atom

    __shared__ float mpsS[NAT_][DIM_];      // embeddings -> mpsn
    __shared__ float conS[NAT_][DIM_];
    __shared__ float adjS[NAT_][NAT_];
    __shared__ int   bSh[8][NAT_];
    __shared__ float redS[NAT_][2];
    __shared__ float nrmS[NAT_];
    __shared__ float sb8[8][DIM_];
    __shared__ float tnp8[8][DIM_];

    // embeddings: 2048 elems / 1024 threads = 2 each
    {
        int j = t >> 7, cc = t & 127;
        mpsS[j][cc] = Efp[(size_t)fp[base + j] * DIM_ + cc];
        j += 8;
        mpsS[j][cc] = Efp[(size_t)fp[base + j] * DIM_ + cc];
    }
    if (t < 256) {
        const int j = t >> 4, i = t & 15;
        adjS[j][i] = adj[(size_t)(base + j) * NTOT_ + base + i];
    } else if (t < 384) {
        const int tt = t - 256, j = tt >> 4, i = tt & 15;
        bSh[j][i] = bidx[(size_t)(base + 8 * h + j) * NTOT_ + base + i];
    }
    __syncthreads();

    // contri for atoms j0, j1
    float a0 = bfp[c];
    float a1 = a0;
    #pragma unroll 8
    for (int k = 0; k < DIM_; ++k) {
        const float w = Wfp[(size_t)k * DIM_ + c];
        a0 += mpsS[j0][k] * w;
        a1 += mpsS[j1][k] * w;
    }
    conS[j0][c] = fmaxf(a0, 0.0f);
    conS[j1][c] = fmaxf(a1, 0.0f);
    __syncthreads();

    // message + row L2 norm for atoms j0, j1
    float ms0 = mpsS[j0][c], ms1 = mpsS[j1][c];
    #pragma unroll
    for (int i = 0; i < NAT_; ++i) {
        const float cv = conS[i][c];
        ms0 += adjS[j0][i] * cv;
        ms1 += adjS[j1][i] * cv;
    }
    float v0 = ms0 * ms0, v1 = ms1 * ms1;
    #pragma unroll
    for (int o = 32; o > 0; o >>= 1) {
        v0 += __shfl_xor(v0, o, 64);
        v1 += __shfl_xor(v1, o, 64);
    }
    const int half = (t >> 6) & 1;
    if ((t & 63) == 0) { redS[j0][half] = v0; redS[j1][half] = v1; }
    __syncthreads();
    if (t < NAT_) nrmS[t] = fmaxf(sqrtf(redS[t][0] + redS[t][1]), EPSF_);
    __syncthreads();
    mpsS[j0][c] = ms0 / nrmS[j0];
    mpsS[j1][c] = ms1 / nrmS[j1];
    __syncthreads();

    // bond gather for owned atom jg: 16 batched loads in flight
    {
        const float e0 = Ebond[c];
        float nsq = OFFB_ * e0 * e0;
        int bb[NAT_];
        #pragma unroll
        for (int i = 0; i < NAT_; ++i) bb[i] = bSh[s][i];
        float ev[NAT_];
        #pragma unroll
        for (int i = 0; i < NAT_; ++i) ev[i] = Ebond[(size_t)bb[i] * DIM_ + c];
        #pragma unroll
        for (int i = 0; i < NAT_; ++i) nsq += ev[i] * ev[i];
        const float msc = mpsS[jg][c] / fmaxf(sqrtf(nsq), EPSF_);
        float tj = 0.0f;
        #pragma unroll
        for (int i = 0; i < NAT_; ++i) tj += ev[i] * mpsS[i][c];
        sb8[s][c]  = msc;
        tnp8[s][c] = msc * tj;
    }
    __syncthreads();

    if (s == 0) {
        float Tn = 0.0f, Sb = 0.0f;
        #pragma unroll
        for (int q = 0; q < 8; ++q) { Tn += tnp8[q][c]; Sb += sb8[q][c]; }
        TnP_g[(size_t)b * DIM_ + c] = Tn;
        SbP_g[(size_t)b * DIM_ + c] = Sb;
    } else if (s == 1 && h == 0) {
        float mb = 0.0f;
        #pragma unroll
        for (int i = 0; i < NAT_; ++i) mb += mpsS[i][c];
        Mb_g[(size_t)m * DIM_ + c] = mb;
    }
}

// Kernel B: 64 blocks x 512 threads. S -> tn -> MLP -> out, slot-split d-loops.
__global__ __launch_bounds__(512) void kB(const float* __restrict__ Ebond,
                                          const float* __restrict__ TnP_g,
                                          const float* __restrict__ SbP_g,
                                          const float* __restrict__ Mb_g,
                                          const float* __restrict__ W0, const float* __restrict__ b0,
                                          const float* __restrict__ W1, const float* __restrict__ b1,
                                          const float* __restrict__ Wp, const float* __restrict__ bp,
                                          float* __restrict__ out) {
    const int m = blockIdx.x;
    const int t = threadIdx.x;
    const int c = t & 127;
    const int s = t >> 7;
    __shared__ float w4[4][DIM_];
    __shared__ float vS[DIM_];
    __shared__ float tnS[DIM_];
    __shared__ float r2[2];

    // S: sum of 128 partials, slot s covers 32
    {
        float S = 0.0f;
        float tv[32];
        #pragma unroll
        for (int r = 0; r < 32; ++r)
            tv[r] = SbP_g[(size_t)(s * 32 + r) * DIM_ + c];
        #pragma unroll
        for (int r = 0; r < 32; ++r) S += tv[r];
        w4[s][c] = S;
    }
    __syncthreads();
    if (s == 0) {
        const float Sall = w4[0][c] + w4[1][c] + w4[2][c] + w4[3][c];
        const float Sb_m = SbP_g[(size_t)(2 * m) * DIM_ + c] + SbP_g[(size_t)(2 * m + 1) * DIM_ + c];
        const float Tn_m = TnP_g[(size_t)(2 * m) * DIM_ + c] + TnP_g[(size_t)(2 * m + 1) * DIM_ + c];
        vS[c] = Tn_m + Ebond[c] * (Sall - Sb_m) * Mb_g[(size_t)m * DIM_ + c];
    }
    __syncthreads();

    // layer 1, d-loop split over slots
    {
        float a1 = 0.0f;
        #pragma unroll 8
        for (int r = 0; r < 32; ++r) {
            const int d = s * 32 + r;
            a1 += vS[d] * W0[(size_t)d * DIM_ + c];
        }
        w4[s][c] = a1;
    }
    __syncthreads();
    if (s == 0) tnS[c] = fmaxf(w4[0][c] + w4[1][c] + w4[2][c] + w4[3][c] + b0[c], 0.0f);
    __syncthreads();
    {
        float a2 = 0.0f;
        #pragma unroll 8
        for (int r = 0; r < 32; ++r) {
            const int d = s * 32 + r;
            a2 += tnS[d] * W1[(size_t)d * DIM_ + c];
        }
        w4[s][c] = a2;
    }
    __syncthreads();
    if (s == 0) {
        const float x1 = fmaxf(w4[0][c] + w4[1][c] + w4[2][c] + w4[3][c] + b1[c], 0.0f);
        float vv = x1 * Wp[c];
        #pragma unroll
        for (int o = 32; o > 0; o >>= 1) vv += __shfl_xor(vv, o, 64);
        if ((c & 63) == 0) r2[c >> 6] = vv;
    }
    __syncthreads();
    if (t == 0) out[m] = r2[0] + r2[1] + bp[0];
}

extern "C" void kernel_launch(void* const* d_in, const int* in_sizes, int n_in,
                              void* d_out, int out_size, void* d_ws, size_t ws_size,
                              hipStream_t stream) {
    const int*   fingerprints = (const int*)  d_in[0];
    const float* adjacency    = (const float*)d_in[1];
    const int*   bond_index   = (const int*)  d_in[2];
    const float* E_fp         = (const float*)d_in[3];
    const float* E_bond       = (const float*)d_in[4];
    const float* W_fp         = (const float*)d_in[5];
    const float* b_fp         = (const float*)d_in[6];
    const float* W_out0       = (const float*)d_in[7];
    const float* b_out0       = (const float*)d_in[8];
    const float* W_out1       = (const float*)d_in[9];
    const float* b_out1       = (const float*)d_in[10];
    const float* W_prop       = (const float*)d_in[11];
    const float* b_prop       = (const float*)d_in[12];
    float* out = (float*)d_out;

    float* ws = (float*)d_ws;
    const size_t PD = (size_t)128 * DIM_;
    float* TnP = ws;                 // [128,128]
    float* SbP = ws + PD;            // [128,128]
    float* Mb  = ws + 2 * PD;        // [64,128]

    kA<<<128, 1024, 0, stream>>>(fingerprints, E_fp, W_fp, b_fp, adjacency, bond_index,
                                 E_bond, TnP, SbP, Mb);
    kB<<<BMOL_, 512, 0, stream>>>(E_bond, TnP, SbP, Mb,
                                  W_out0, b_out0, W_out1, b_out1, W_prop, b_prop, out);
}